// Round 19
// baseline (440.295 us; speedup 1.0000x reference)
//
#include <hip/hip_runtime.h>
#include <hip/hip_bf16.h>

typedef __hip_bfloat16 bf16;
typedef __attribute__((ext_vector_type(8))) short short8;
typedef __attribute__((ext_vector_type(4))) float floatx4;

#define NPIX  131072
#define BATCH 2
#define HH    256
#define WW    256
#define CDIM  96
#define C3    288
#define HEADS 2
#define CH    48
#define HIDN  255
#define HWSZ  65536
#define EPSV  1e-5f

__device__ __forceinline__ float b2f(bf16 v) { return __bfloat162float(v); }
__device__ __forceinline__ bf16  f2b(float v) { return __float2bfloat16(v); }
__device__ __forceinline__ short f2bs(float v) { bf16 h = __float2bfloat16(v); return *reinterpret_cast<short*>(&h); }
__device__ __forceinline__ float lo16(unsigned u) { return __uint_as_float(u << 16); }
__device__ __forceinline__ float hi16(unsigned u) { return __uint_as_float(u & 0xffff0000u); }
__device__ __forceinline__ unsigned packbf(float lo, float hi) {
  return ((unsigned)(unsigned short)f2bs(hi) << 16) | (unsigned)(unsigned short)f2bs(lo);
}

// exact-erf gelu via Abramowitz-Stegun 7.1.26 (|err| <= 1.5e-7)
__device__ __forceinline__ float fast_gelu(float x) {
  float ax = fabsf(x) * 0.70710678118654752440f;
  float t  = 1.f / (1.f + 0.3275911f * ax);
  float p  = ((((1.061405429f * t - 1.453152027f) * t + 1.421413741f) * t
               - 0.284496736f) * t + 0.254829592f) * t;
  float er = 1.f - p * __expf(-ax * ax);
  er = copysignf(er, x);
  return 0.5f * x * (1.f + er);
}

// ======== One-shot weight transpose to k-major bf16 (+ padded f32 dw table) ====
__global__ __launch_bounds__(256) void prep_wt(
    const float* __restrict__ qkv_w, const float* __restrict__ ffn_in_w,
    const float* __restrict__ ffn_out_w, const float* __restrict__ ffn_dw,
    bf16* __restrict__ WQ, bf16* __restrict__ WF1, bf16* __restrict__ WF2,
    bf16* __restrict__ WO, float* __restrict__ WDW)
{
  int gid = blockIdx.x * 256 + threadIdx.x;
  if (gid < 27648) {                       // 288*96
    int n = gid / 96, k = gid - n * 96;
    WQ[gid] = f2b(qkv_w[k * C3 + n]);
  } else if (gid < 27648 + 24576) {        // 256*96
    int g = gid - 27648;
    int n = g / 96, k = g - n * 96;
    WF1[g] = f2b(n < HIDN ? ffn_in_w[k * (2 * HIDN) + n] : 0.f);
  } else if (gid < 27648 + 49152) {
    int g = gid - 27648 - 24576;
    int n = g / 96, k = g - n * 96;
    WF2[g] = f2b(n < HIDN ? ffn_in_w[k * (2 * HIDN) + HIDN + n] : 0.f);
  } else if (gid < 101376) {               // 96*256
    int g = gid - 27648 - 49152;
    int n = g / 256, k = g - n * 256;
    WO[g] = f2b(k < HIDN ? ffn_out_w[k * CDIM + n] : 0.f);
  } else {                                 // WDW [9][512] f32, cols 255/511 = 0
    int idx = gid - 101376;                // 0..4607
    if (idx < 4608) {
      int c = idx & 511;
      float v = 0.f;
      if (c < 255)                 v = ffn_dw[(idx >> 9) * 510 + c];
      else if (c >= 256 && c < 511) v = ffn_dw[(idx >> 9) * 510 + (c - 1)];
      WDW[idx] = v;
    }
  }
}

// ======== FFN-out GEMM, two-phase K-split LDS panel (r16) ========
__global__ __launch_bounds__(256, 2) void mfma_gemm_out(
    const bf16* __restrict__ A, const bf16* __restrict__ Wt,  // Wt [96][256]
    const float* __restrict__ res, float* __restrict__ outp)
{
  constexpr int KP = 136;
  __shared__ __align__(16) bf16 Bs[96 * KP];      // 26.1 KB
  const int tid  = threadIdx.x;
  const long bm  = (long)blockIdx.x * 128;
  const int lane = tid & 63;
  const int wv   = tid >> 6;
  const int m15  = lane & 15;
  const int quad = lane >> 4;

  short8 areg[2][8];
  #pragma unroll
  for (int rt = 0; rt < 2; ++rt) {
    const bf16* ap = A + (bm + wv * 32 + rt * 16 + m15) * 256 + quad * 8;
    #pragma unroll
    for (int kk = 0; kk < 8; ++kk)
      areg[rt][kk] = *reinterpret_cast<const short8*>(ap + kk * 32);
  }

  floatx4 acc[2][6];
  #pragma unroll
  for (int rt = 0; rt < 2; ++rt)
    #pragma unroll
    for (int ct = 0; ct < 6; ++ct)
      acc[rt][ct] = (floatx4){0.f, 0.f, 0.f, 0.f};

  #pragma unroll 1
  for (int half = 0; half < 2; ++half) {
    if (half) __syncthreads();             // drain reads of previous half
    for (int idx = tid; idx < 96 * 16; idx += 256) {
      int n = idx >> 4, seg = idx & 15;
      *reinterpret_cast<uint4*>(&Bs[n * KP + seg * 8]) =
          *reinterpret_cast<const uint4*>(Wt + n * 256 + half * 128 + seg * 8);
    }
    __syncthreads();
    #pragma unroll
    for (int kk = 0; kk < 4; ++kk)
      #pragma unroll
      for (int ct = 0; ct < 6; ++ct) {
        short8 b = *reinterpret_cast<const short8*>(&Bs[(ct * 16 + m15) * KP + kk * 32 + quad * 8]);
        #pragma unroll
        for (int rt = 0; rt < 2; ++rt)
          acc[rt][ct] = __builtin_amdgcn_mfma_f32_16x16x32_bf16(areg[rt][half * 4 + kk], b, acc[rt][ct], 0, 0, 0);
      }
  }

  #pragma unroll
  for (int rt = 0; rt < 2; ++rt)
    #pragma unroll
    for (int ct = 0; ct < 6; ++ct) {
      int col = ct * 16 + m15;
      #pragma unroll
      for (int r = 0; r < 4; ++r) {
        long row = bm + wv * 32 + rt * 16 + quad * 4 + r;
        outp[row * CDIM + col] = acc[rt][ct][r] + res[row * CDIM + col];
      }
    }
}

// ======== FFN-in GEMM, LDS-staged weight panel (r14) ========
__global__ __launch_bounds__(256, 2) void mfma_gemm_ffn(
    const bf16* __restrict__ A,
    const bf16* __restrict__ Wt1, const bf16* __restrict__ Wt2,
    bf16* __restrict__ out1, bf16* __restrict__ out2)
{
  constexpr int KP = 104;
  __shared__ __align__(16) bf16 Bs[128 * KP];     // 26.6 KB
  const bf16* Wt  = (blockIdx.z & 2) ? Wt2 : Wt1;
  bf16* outp      = (blockIdx.z & 2) ? out2 : out1;
  const int nh    = (blockIdx.z & 1) * 128;       // column half
  const int tid  = threadIdx.x;
  const long bm  = (long)blockIdx.x * 128;
  const int lane = tid & 63;
  const int wv   = tid >> 6;
  const int m15  = lane & 15;
  const int quad = lane >> 4;

  for (int idx = tid; idx < 128 * 12; idx += 256) {
    int n = idx / 12, seg = idx - n * 12;
    *reinterpret_cast<uint4*>(&Bs[n * KP + seg * 8]) =
        *reinterpret_cast<const uint4*>(Wt + (nh + n) * 96 + seg * 8);
  }

  short8 areg[2][3];
  #pragma unroll
  for (int rt = 0; rt < 2; ++rt) {
    const bf16* ap = A + (bm + wv * 32 + rt * 16 + m15) * CDIM + quad * 8;
    #pragma unroll
    for (int kk = 0; kk < 3; ++kk)
      areg[rt][kk] = *reinterpret_cast<const short8*>(ap + kk * 32);
  }

  __syncthreads();

  floatx4 acc[2][8];
  #pragma unroll
  for (int rt = 0; rt < 2; ++rt)
    #pragma unroll
    for (int ct = 0; ct < 8; ++ct)
      acc[rt][ct] = (floatx4){0.f, 0.f, 0.f, 0.f};

  #pragma unroll
  for (int kk = 0; kk < 3; ++kk)
    #pragma unroll
    for (int ct = 0; ct < 8; ++ct) {
      short8 b = *reinterpret_cast<const short8*>(&Bs[(ct * 16 + m15) * KP + kk * 32 + quad * 8]);
      #pragma unroll
      for (int rt = 0; rt < 2; ++rt)
        acc[rt][ct] = __builtin_amdgcn_mfma_f32_16x16x32_bf16(areg[rt][kk], b, acc[rt][ct], 0, 0, 0);
    }

  #pragma unroll
  for (int rt = 0; rt < 2; ++rt)
    #pragma unroll
    for (int ct = 0; ct < 8; ++ct) {
      int col = nh + ct * 16 + m15;
      #pragma unroll
      for (int r = 0; r < 4; ++r) {
        long row = bm + wv * 32 + rt * 16 + quad * 4 + r;
        outp[row * 256 + col] = f2b(acc[rt][ct][r]);
      }
    }
}

// ======== qkv GEMM + fused LN, two-phase N-split panel (r17) ========
__global__ __launch_bounds__(256, 2) void mfma_gemm_lnA(
    const float* __restrict__ X, const float* __restrict__ gam, const float* __restrict__ bet,
    const bf16* __restrict__ Wt,   // [288][96]
    bf16* __restrict__ outp)
{
  constexpr int KP = 104;
  __shared__ __align__(16) bf16 Bs[144 * KP];     // 30.0 KB
  const int tid  = threadIdx.x;
  const long bm  = (long)blockIdx.x * 128;
  const int lane = tid & 63;
  const int wv   = tid >> 6;
  const int m15  = lane & 15;
  const int quad = lane >> 4;

  // stage phase-0 panel (rows 0..143); overlaps with LN math below
  for (int idx = tid; idx < 144 * 12; idx += 256) {
    int n = idx / 12, seg = idx - n * 12;
    *reinterpret_cast<uint4*>(&Bs[n * KP + seg * 8]) =
        *reinterpret_cast<const uint4*>(Wt + n * 96 + seg * 8);
  }

  float xv[2][24];
  #pragma unroll
  for (int rt = 0; rt < 2; ++rt) {
    const float* xp = X + (bm + wv * 32 + rt * 16 + m15) * CDIM + quad * 8;
    #pragma unroll
    for (int kk = 0; kk < 3; ++kk) {
      float4 t0 = *reinterpret_cast<const float4*>(xp + kk * 32);
      float4 t1 = *reinterpret_cast<const float4*>(xp + kk * 32 + 4);
      xv[rt][kk * 8 + 0] = t0.x; xv[rt][kk * 8 + 1] = t0.y; xv[rt][kk * 8 + 2] = t0.z; xv[rt][kk * 8 + 3] = t0.w;
      xv[rt][kk * 8 + 4] = t1.x; xv[rt][kk * 8 + 5] = t1.y; xv[rt][kk * 8 + 6] = t1.z; xv[rt][kk * 8 + 7] = t1.w;
    }
  }
  float gv[24], bv[24];
  #pragma unroll
  for (int kk = 0; kk < 3; ++kk) {
    float4 g0 = *reinterpret_cast<const float4*>(gam + kk * 32 + quad * 8);
    float4 g1 = *reinterpret_cast<const float4*>(gam + kk * 32 + quad * 8 + 4);
    float4 b0 = *reinterpret_cast<const float4*>(bet + kk * 32 + quad * 8);
    float4 b1 = *reinterpret_cast<const float4*>(bet + kk * 32 + quad * 8 + 4);
    gv[kk * 8 + 0] = g0.x; gv[kk * 8 + 1] = g0.y; gv[kk * 8 + 2] = g0.z; gv[kk * 8 + 3] = g0.w;
    gv[kk * 8 + 4] = g1.x; gv[kk * 8 + 5] = g1.y; gv[kk * 8 + 6] = g1.z; gv[kk * 8 + 7] = g1.w;
    bv[kk * 8 + 0] = b0.x; bv[kk * 8 + 1] = b0.y; bv[kk * 8 + 2] = b0.z; bv[kk * 8 + 3] = b0.w;
    bv[kk * 8 + 4] = b1.x; bv[kk * 8 + 5] = b1.y; bv[kk * 8 + 6] = b1.z; bv[kk * 8 + 7] = b1.w;
  }

  short8 areg[2][3];
  #pragma unroll
  for (int rt = 0; rt < 2; ++rt) {
    float s = 0.f, sq = 0.f;
    #pragma unroll
    for (int e = 0; e < 24; ++e) { s += xv[rt][e]; sq += xv[rt][e] * xv[rt][e]; }
    s  += __shfl_xor(s, 16);  s  += __shfl_xor(s, 32);
    sq += __shfl_xor(sq, 16); sq += __shfl_xor(sq, 32);
    float mean = s * (1.f / 96.f);
    float var  = sq * (1.f / 96.f) - mean * mean;
    float rstd = rsqrtf(var + EPSV);
    #pragma unroll
    for (int kk = 0; kk < 3; ++kk)
      #pragma unroll
      for (int j = 0; j < 8; ++j)
        areg[rt][kk][j] = f2bs((xv[rt][kk * 8 + j] - mean) * rstd * gv[kk * 8 + j] + bv[kk * 8 + j]);
  }

  #pragma unroll 1
  for (int ph = 0; ph < 2; ++ph) {
    if (ph) {
      __syncthreads();                     // drain phase-0 panel reads
      for (int idx = tid; idx < 144 * 12; idx += 256) {
        int n = idx / 12, seg = idx - n * 12;
        *reinterpret_cast<uint4*>(&Bs[n * KP + seg * 8]) =
            *reinterpret_cast<const uint4*>(Wt + (144 + n) * 96 + seg * 8);
      }
    }
    __syncthreads();

    floatx4 acc[2][9];
    #pragma unroll
    for (int rt = 0; rt < 2; ++rt)
      #pragma unroll
      for (int ct = 0; ct < 9; ++ct)
        acc[rt][ct] = (floatx4){0.f, 0.f, 0.f, 0.f};

    #pragma unroll
    for (int kk = 0; kk < 3; ++kk)
      #pragma unroll
      for (int ct = 0; ct < 9; ++ct) {
        short8 b = *reinterpret_cast<const short8*>(&Bs[(ct * 16 + m15) * KP + kk * 32 + quad * 8]);
        #pragma unroll
        for (int rt = 0; rt < 2; ++rt)
          acc[rt][ct] = __builtin_amdgcn_mfma_f32_16x16x32_bf16(areg[rt][kk], b, acc[rt][ct], 0, 0, 0);
      }

    #pragma unroll
    for (int rt = 0; rt < 2; ++rt)
      #pragma unroll
      for (int ct = 0; ct < 9; ++ct) {
        int col = ph * 144 + ct * 16 + m15;
        #pragma unroll
        for (int r = 0; r < 4; ++r) {
          long row = bm + wv * 32 + rt * 16 + quad * 4 + r;
          outp[row * C3 + col] = f2b(acc[rt][ct][r]);
        }
      }
  }
}

// ======== attn-out GEMM (v-plane @ M_b^T) + residual + fused LN2, staged Mt ====
__global__ __launch_bounds__(256, 2) void mfma_gemm_attn(
    const bf16* __restrict__ A, const bf16* __restrict__ Mt,
    const float* __restrict__ res, const float* __restrict__ gam, const float* __restrict__ bet,
    float* __restrict__ outp, bf16* __restrict__ y2)
{
  constexpr int KP = 104;
  __shared__ __align__(16) bf16 Bs[96 * KP];      // 20 KB
  const int tid  = threadIdx.x;
  const long bm  = (long)blockIdx.x * 128;
  const int lane = tid & 63;
  const int wv   = tid >> 6;
  const int m15  = lane & 15;
  const int quad = lane >> 4;

  const bf16* mp = Mt + (bm >> 16) * (CDIM * CDIM);
  for (int idx = tid; idx < 96 * 12; idx += 256) {
    int n = idx / 12, seg = idx - n * 12;
    *reinterpret_cast<uint4*>(&Bs[n * KP + seg * 8]) =
        *reinterpret_cast<const uint4*>(mp + n * 96 + seg * 8);
  }

  short8 areg[2][3];
  #pragma unroll
  for (int rt = 0; rt < 2; ++rt) {
    const bf16* ap = A + (bm + wv * 32 + rt * 16 + m15) * 96 + quad * 8;
    #pragma unroll
    for (int kk = 0; kk < 3; ++kk)
      areg[rt][kk] = *reinterpret_cast<const short8*>(ap + kk * 32);
  }

  __syncthreads();

  floatx4 acc[2][6];
  #pragma unroll
  for (int rt = 0; rt < 2; ++rt)
    #pragma unroll
    for (int ct = 0; ct < 6; ++ct)
      acc[rt][ct] = (floatx4){0.f, 0.f, 0.f, 0.f};

  #pragma unroll
  for (int kk = 0; kk < 3; ++kk)
    #pragma unroll
    for (int ct = 0; ct < 6; ++ct) {
      short8 b = *reinterpret_cast<const short8*>(&Bs[(ct * 16 + m15) * KP + kk * 32 + quad * 8]);
      #pragma unroll
      for (int rt = 0; rt < 2; ++rt)
        acc[rt][ct] = __builtin_amdgcn_mfma_f32_16x16x32_bf16(areg[rt][kk], b, acc[rt][ct], 0, 0, 0);
    }

  float gv[6], bv[6];
  #pragma unroll
  for (int ct = 0; ct < 6; ++ct) { gv[ct] = gam[ct * 16 + m15]; bv[ct] = bet[ct * 16 + m15]; }

  #pragma unroll
  for (int rt = 0; rt < 2; ++rt)
    #pragma unroll
    for (int r = 0; r < 4; ++r) {
      long row = bm + wv * 32 + rt * 16 + quad * 4 + r;
      float v[6];
      float s = 0.f, sq = 0.f;
      #pragma unroll
      for (int ct = 0; ct < 6; ++ct) {
        v[ct] = acc[rt][ct][r] + res[row * CDIM + ct * 16 + m15];
        s += v[ct]; sq += v[ct] * v[ct];
      }
      #pragma unroll
      for (int off = 8; off; off >>= 1) { s += __shfl_xor(s, off); sq += __shfl_xor(sq, off); }
      float mean = s * (1.f / 96.f);
      float var  = sq * (1.f / 96.f) - mean * mean;
      float rstd = rsqrtf(var + EPSV);
      #pragma unroll
      for (int ct = 0; ct < 6; ++ct) {
        int col = ct * 16 + m15;
        outp[row * CDIM + col] = v[ct];
        y2[row * CDIM + col] = f2b((v[ct] - mean) * rstd * gv[ct] + bv[ct]);
      }
    }
}

// ======== qkv depthwise 3x3 conv -> plane-major [3][NPIX][96] ========
// dx-major loop: 4 unique input rows loaded+extracted ONCE, feeding both
// output-row accumulators (rows r+1,r+2 were read+extracted twice before:
// -33% ds_read, -33% lo16/hi16 VALU on a ~65%-VALU-busy kernel family).
__global__ __launch_bounds__(384, 2) void dwconv_plane(
    const bf16* __restrict__ in,      // [NPIX][288] pre-dwconv qkv
    const float* __restrict__ kw,     // qkv_dw [9][288] f32
    bf16* __restrict__ outbase)       // [3][NPIX][96]
{
  __shared__ uint4 sm[12][19 * 10];
  const int tid = threadIdx.x;
  const int tx0 = blockIdx.x * 16;
  const int ty0 = (blockIdx.y & 31) * 8;
  const int b   = blockIdx.y >> 5;
  const int pl  = blockIdx.z;        // 0=q 1=k 2=v
  const int c0  = pl * 96;
  const long bbase = (long)b * HWSZ;
  bf16* out = outbase + (size_t)pl * NPIX * 96;

  const int lane = tid & 63;
  const int wv   = tid >> 6;         // 0..5

  // per-wave staging: wave wv owns slices wv and wv+6
  for (int f = lane; f < 180; f += 64) {
    int row = f / 18, px = f - row * 18;
    int y = ty0 + row - 1, xx = tx0 + px - 1;
    uint4 ua = make_uint4(0u, 0u, 0u, 0u), ub = ua;
    if ((unsigned)y < (unsigned)HH && (unsigned)xx < (unsigned)WW) {
      const bf16* p = in + (bbase + (long)y * WW + xx) * C3 + c0;
      ua = *reinterpret_cast<const uint4*>(p + wv * 8);
      ub = *reinterpret_cast<const uint4*>(p + (wv + 6) * 8);
    }
    sm[wv][row * 19 + px]     = ua;
    sm[wv + 6][row * 19 + px] = ub;
  }
  asm volatile("s_waitcnt lgkmcnt(0)" ::: "memory");
  __builtin_amdgcn_sched_barrier(0);

  const int x  = lane & 15;
  const int yg = lane >> 4;          // 0..3, 2 output rows per thread

  #pragma unroll 1
  for (int cgi = 0; cgi < 2; ++cgi) {
    const int cg = wv + cgi * 6;     // 0..11
    // wave-uniform channel base -> scalar (s_load) weight fetch
    const int cbu = __builtin_amdgcn_readfirstlane(c0 + cg * 8);
    float wgt[9][8];
    #pragma unroll
    for (int t = 0; t < 9; ++t) {
      float4 w0 = *reinterpret_cast<const float4*>(kw + t * C3 + cbu);
      float4 w1 = *reinterpret_cast<const float4*>(kw + t * C3 + cbu + 4);
      wgt[t][0] = w0.x; wgt[t][1] = w0.y; wgt[t][2] = w0.z; wgt[t][3] = w0.w;
      wgt[t][4] = w1.x; wgt[t][5] = w1.y; wgt[t][6] = w1.z; wgt[t][7] = w1.w;
    }

    float a0[8] = {0.f, 0.f, 0.f, 0.f, 0.f, 0.f, 0.f, 0.f};
    float a1[8] = {0.f, 0.f, 0.f, 0.f, 0.f, 0.f, 0.f, 0.f};
    #pragma unroll
    for (int dxi = 0; dxi < 3; ++dxi) {
      uint4 rr[4];
      #pragma unroll
      for (int i = 0; i < 4; ++i)
        rr[i] = sm[cg][(yg * 2 + i) * 19 + x + dxi];
      #pragma unroll
      for (int i = 0; i < 4; ++i) {
        float e[8];
        e[0] = lo16(rr[i].x); e[1] = hi16(rr[i].x);
        e[2] = lo16(rr[i].y); e[3] = hi16(rr[i].y);
        e[4] = lo16(rr[i].z); e[5] = hi16(rr[i].z);
        e[6] = lo16(rr[i].w); e[7] = hi16(rr[i].w);
        #pragma unroll
        for (int j = 0; j < 8; ++j) {
          if (i <= 2) a0[j] += e[j] * wgt[i * 3 + dxi][j];
          if (i >= 1) a1[j] += e[j] * wgt[(i - 1) * 3 + dxi][j];
        }
      }
    }

    bf16* op0 = out + (bbase + (long)(ty0 + yg * 2) * WW + tx0 + x) * 96 + cg * 8;
    bf16* op1 = out + (bbase + (long)(ty0 + yg * 2 + 1) * WW + tx0 + x) * 96 + cg * 8;
    __align__(16) bf16 ov[8];
    #pragma unroll
    for (int j = 0; j < 8; ++j) ov[j] = f2b(a0[j]);
    *reinterpret_cast<uint4*>(op0) = *reinterpret_cast<const uint4*>(ov);
    #pragma unroll
    for (int j = 0; j < 8; ++j) ov[j] = f2b(a1[j]);
    *reinterpret_cast<uint4*>(op1) = *reinterpret_cast<const uint4*>(ov);

    __builtin_amdgcn_sched_barrier(0);   // one wgt set live at a time
  }
}

// ======== Fused FFN gate v6: dx-major row-sharing conv (VALU cut) ========
__global__ __launch_bounds__(512, 2) void dwgate512(
    const bf16* __restrict__ t1, const bf16* __restrict__ t2,
    const float* __restrict__ wdw, bf16* __restrict__ out)
{
  __shared__ uint4 sm[8][19 * 10];
  const int tid = threadIdx.x;
  const int tx0 = blockIdx.x * 16;
  const int ty0 = (blockIdx.y & 31) * 8;
  const long bbase = (long)(blockIdx.y >> 5) * HWSZ;
  const int c0  = blockIdx.z * 64;

  const int lane = tid & 63;
  const int wv   = tid >> 6;         // 0..7 = this wave's ch-group
  const int cb   = c0 + wv * 8;
  const int cbu  = __builtin_amdgcn_readfirstlane(cb);

  // ---- stage t1 into this wave's slice; preload t2 into regs (async split) ----
  uint4 t2r[3];
  #pragma unroll
  for (int i = 0; i < 3; ++i) {
    int f = lane + i * 64;
    int row = f / 18, px = f - row * 18;
    int y = ty0 + row - 1, xx = tx0 + px - 1;
    bool ok = (f < 180) && ((unsigned)y < (unsigned)HH) && ((unsigned)xx < (unsigned)WW);
    long base = (bbase + (long)y * WW + xx) * 256 + cb;
    uint4 u1 = make_uint4(0u, 0u, 0u, 0u);
    t2r[i]   = make_uint4(0u, 0u, 0u, 0u);
    if (ok) {
      u1     = *reinterpret_cast<const uint4*>(t1 + base);
      t2r[i] = *reinterpret_cast<const uint4*>(t2 + base);
    }
    if (f < 180) sm[wv][row * 19 + px] = u1;
  }
  asm volatile("s_waitcnt lgkmcnt(0)" ::: "memory");
  __builtin_amdgcn_sched_barrier(0);

  const int x  = lane & 15;
  const int yg = lane >> 4;          // 0..3, 2 output rows per thread

  unsigned gp[8];                    // gelu(conv1) packed 2xbf16: [0..3] row0, [4..7] row1
  float wgt[9][8];

  // ---- pass 1: conv t1 (sm[wv]) -> gelu, packed regs; dx-major row sharing ----
  #pragma unroll
  for (int t = 0; t < 9; ++t) {
    float4 w0 = *reinterpret_cast<const float4*>(wdw + t * 512 + cbu);
    float4 w1 = *reinterpret_cast<const float4*>(wdw + t * 512 + cbu + 4);
    wgt[t][0] = w0.x; wgt[t][1] = w0.y; wgt[t][2] = w0.z; wgt[t][3] = w0.w;
    wgt[t][4] = w1.x; wgt[t][5] = w1.y; wgt[t][6] = w1.z; wgt[t][7] = w1.w;
  }
  {
    float a0[8] = {0.f, 0.f, 0.f, 0.f, 0.f, 0.f, 0.f, 0.f};
    float a1[8] = {0.f, 0.f, 0.f, 0.f, 0.f, 0.f, 0.f, 0.f};
    #pragma unroll
    for (int dxi = 0; dxi < 3; ++dxi) {
      uint4 rr[4];
      #pragma unroll
      for (int i = 0; i < 4; ++i)
        rr[i] = sm[wv][(yg * 2 + i) * 19 + x + dxi];
      #pragma unroll
      for (int i = 0; i < 4; ++i) {
        float e[8];
        e[0] = lo16(rr[i].x); e[1] = hi16(rr[i].x);
        e[2] = lo16(rr[i].y); e[3] = hi16(rr[i].y);
        e[4] = lo16(rr[i].z); e[5] = hi16(rr[i].z);
        e[6] = lo16(rr[i].w); e[7] = hi16(rr[i].w);
        #pragma unroll
        for (int j = 0; j < 8; ++j) {
          if (i <= 2) a0[j] += e[j] * wgt[i * 3 + dxi][j];
          if (i >= 1) a1[j] += e[j] * wgt[(i - 1) * 3 + dxi][j];
        }
      }
    }
    #pragma unroll
    for (int p = 0; p < 4; ++p) {
      gp[p]     = packbf(fast_gelu(a0[2 * p]), fast_gelu(a0[2 * p + 1]));
      gp[4 + p] = packbf(fast_gelu(a1[2 * p]), fast_gelu(a1[2 * p + 1]));
    }
  }

  // ---- restage t2 into the same slice (pass-1 reads consumed; DS in-order) ----
  asm volatile("s_waitcnt lgkmcnt(0)" ::: "memory");
  __builtin_amdgcn_sched_barrier(0);
  #pragma unroll
  for (int i = 0; i < 3; ++i) {
    int f = lane + i * 64;
    int row = f / 18, px = f - row * 18;
    if (f < 180) sm[wv][row * 19 + px] = t2r[i];
  }
  asm volatile("s_waitcnt lgkmcnt(0)" ::: "memory");
  __builtin_amdgcn_sched_barrier(0);

  // ---- pass 2: conv t2 (sm[wv]), multiply, store; dx-major row sharing ----
  #pragma unroll
  for (int t = 0; t < 9; ++t) {
    float4 w0 = *reinterpret_cast<const float4*>(wdw + t * 512 + 256 + cbu);
    float4 w1 = *reinterpret_cast<const float4*>(wdw + t * 512 + 256 + cbu + 4);
    wgt[t][0] = w0.x; wgt[t][1] = w0.y; wgt[t][2] = w0.z; wgt[t][3] = w0.w;
    wgt[t][4] = w1.x; wgt[t][5] = w1.y; wgt[t][6] = w1.z; wgt[t][7] = w1.w;
  }
  {
    float b0[8] = {0.f, 0.f, 0.f, 0.f, 0.f, 0.f, 0.f, 0.f};
    float b1[8] = {0.f, 0.f, 0.f, 0.f, 0.f, 0.f, 0.f, 0.f};
    #pragma unroll
    for (int dxi = 0; dxi < 3; ++dxi) {
      uint4 rr[4];
      #pragma unroll
      for (int i = 0; i < 4; ++i)
        rr[i] = sm[wv][(yg * 2 + i) * 19 + x + dxi];
      #pragma unroll
      for (int i = 0; i < 4; ++i) {
        float e[8];
        e[0] = lo16(rr[i].x); e[1] = hi16(rr[i].x);
        e[2] = lo16(rr[i].y); e[3] = hi16(rr[i].y);
        e[4] = lo16(rr[i].z); e[5] = hi16(rr[i].z);
        e[6] = lo16(rr[i].w); e[7] = hi16(rr[i].w);
        #pragma unroll
        for (int j = 0; j < 8; ++j) {
          if (i <= 2) b0[j] += e[j] * wgt[i * 3 + dxi][j];
          if (i >= 1) b1[j] += e[j] * wgt[(i - 1) * 3 + dxi][j];
        }
      }
    }
    __align__(16) bf16 ov[8];
    bf16* op0 = out + (bbase + (long)(ty0 + yg * 2) * WW + tx0 + x) * 256 + cb;
    #pragma unroll
    for (int p = 0; p < 4; ++p) {
      ov[2 * p]     = f2b(lo16(gp[p]) * b0[2 * p]);
      ov[2 * p + 1] = f2b(hi16(gp[p]) * b0[2 * p + 1]);
    }
    *reinterpret_cast<uint4*>(op0) = *reinterpret_cast<const uint4*>(ov);
    bf16* op1 = out + (bbase + (long)(ty0 + yg * 2 + 1) * WW + tx0 + x) * 256 + cb;
    #pragma unroll
    for (int p = 0; p < 4; ++p) {
      ov[2 * p]     = f2b(lo16(gp[4 + p]) * b1[2 * p]);
      ov[2 * p + 1] = f2b(hi16(gp[4 + p]) * b1[2 * p + 1]);
    }
    *reinterpret_cast<uint4*>(op1) = *reinterpret_cast<const uint4*>(ov);
  }
}

// ======== MFMA Gram + fused q/k L2 norms — q/k planes [NPIX][96] ========
__global__ __launch_bounds__(256) void gram_kernel(
    const bf16* __restrict__ Qp, const bf16* __restrict__ Kp,
    float* __restrict__ Gpart, float* __restrict__ Npart)
{
  constexpr int SP = 264;
  __shared__ __align__(16) char raw[2 * CH * SP * 2];   // 50688 B
  short* qs = (short*)raw;              // [48][SP]
  short* ks = qs + CH * SP;
  const int tid  = threadIdx.x;
  const int bh   = blockIdx.y;
  const long row0 = (long)(bh >> 1) * HWSZ + (long)blockIdx.x * 256;
  const int head = bh & 1;
  const int lane = tid & 63;
  const int wv   = tid >> 6;
  const int m15  = lane & 15;
  const int quad = lane >> 4;

  {
    const short* qsrc = (const short*)(Qp + (row0 + tid) * 96 + head * CH);
    const short* ksrc = (const short*)(Kp + (row0 + tid) * 96 + head * CH);
    #pragma unroll
    for (int v = 0; v < 6; ++v) {
      short8 q8 = *reinterpret_cast<const short8*>(qsrc + v * 8);
      short8 k8 = *reinterpret_cast<const short8*>(ksrc + v * 8);
      #pragma unroll
      for (int j = 0; j < 8; ++j) {
        qs[(v * 8 + j) * SP + tid] = q8[j];
        ks[(v * 8 + j) * SP + tid] = k8[j];
      }
    }
  }
  __syncthreads();

  floatx4 acc[3][3], accq[3], acck[3];
  #pragma unroll
  for (int i = 0; i < 3; ++i) {
    accq[i] = (floatx4){0.f, 0.f, 0.f, 0.f};
    acck[i] = (floatx4){0.f, 0.f, 0.f, 0.f};
    #pragma unroll
    for (int j = 0; j < 3; ++j) acc[i][j] = (floatx4){0.f, 0.f, 0.f, 0.f};
  }

  #pragma unroll
  for (int kk = 0; kk < 2; ++kk) {
    const int s_off = wv * 64 + kk * 32 + quad * 8;
    short8 aq[3], bk[3];
    #pragma unroll
    for (int i = 0; i < 3; ++i) {
      aq[i] = *reinterpret_cast<const short8*>(&qs[(i * 16 + m15) * SP + s_off]);
      bk[i] = *reinterpret_cast<const short8*>(&ks[(i * 16 + m15) * SP + s_off]);
    }
    #pragma unroll
    for (int i = 0; i < 3; ++i) {
      accq[i] = __builtin_amdgcn_mfma_f32_16x16x32_bf16(aq[i], aq[i], accq[i], 0, 0, 0);
      acck[i] = __builtin_amdgcn_mfma_f32_16x16x32_bf16(bk[i], bk[i], acck[i], 0, 0, 0);
      #pragma unroll
      for (int j = 0; j < 3; ++j)
        acc[i][j] = __builtin_amdgcn_mfma_f32_16x16x32_bf16(aq[i], bk[j], acc[i][j], 0, 0, 0);
    }
  }

  __syncthreads();
  float* part  = (float*)raw;            // [4][48*49] = 9408 floats
  float* npart = part + 4 * 48 * 49;     // [4][96]
  const int c_lo = quad * 4;
  #pragma unroll
  for (int i = 0; i < 3; ++i)
    #pragma unroll
    for (int j = 0; j < 3; ++j)
      #pragma unroll
      for (int r = 0; r < 4; ++r)
        part[wv * 2352 + (i * 16 + c_lo + r) * 49 + j * 16 + m15] = acc[i][j][r];
  if (m15 >= c_lo && m15 < c_lo + 4) {
    const int r = m15 - c_lo;
    #pragma unroll
    for (int i = 0; i < 3; ++i) {
      npart[wv * 96 + i * 16 + m15]      = accq[i][r];
      npart[wv * 96 + 48 + i * 16 + m15] = acck[i][r];
    }
  }
  __syncthreads();
  float* Gp = Gpart + ((long)blockIdx.x * 4 + bh) * 2304;
  for (int f = tid; f < 2304; f += 256) {
    int row = f / 48, col = f - row * 48;
    int o = row * 49 + col;
    Gp[f] = part[o] + part[2352 + o] + part[4704 + o] + part[7056 + o];
  }
  if (tid < 96)
    Npart[((long)blockIdx.x * 4 + bh) * 96 + tid] =
        npart[tid] + npart[96 + tid] + npart[192 + tid] + npart[288 + tid];
}

// ---- sum the 256 chunk partials per bh into G / nq / nk ----
__global__ __launch_bounds__(256) void gram_reduce(const float* __restrict__ Gpart,
    const float* __restrict__ Npart, float* __restrict__ G,
    float* __restrict__ nq, float* __restrict__ nk)
{
  const int bh = blockIdx.x;
  const int b = bh >> 1, head = bh & 1;
  if (blockIdx.y < 9) {
    const int f = blockIdx.y * 256 + threadIdx.x;
    float s = 0.f;
    #pragma unroll 8
    for (int c = 0; c < 256; ++c) s += Gpart[((long)c * 4 + bh) * 2304 + f];
    G[(long)bh * 2304 + f] = s;
  } else {
    const int t = threadIdx.x;
    if (t < 96) {
      float s = 0.f;
      #pragma unroll 8
      for (int c = 0; c < 256; ++c) s += Npart[((long)c * 4 + bh) * 96 + t];
      if (t < 48) nq[b * CDIM + head * CH + t] = s;
      else        nk[b * CDIM + head * CH + t - 48] = s;
    }
  }
}

// ---------------- softmax over d of G/(|q||k|)*temp ----------------
__global__ __launch_bounds__(64) void softmax_kernel(const float* __restrict__ G,
    const float* __restrict__ nq, const float* __restrict__ nk,
    const float* __restrict__ temp, float* __restrict__ attn)
{
  int r = blockIdx.x;               // 0..191 = (b*2+head)*48 + c
  int lane = threadIdx.x;
  int bh = r / CH, c = r % CH;
  int b = bh >> 1, head = bh & 1;
  float t  = temp[head];
  float qn = sqrtf(nq[b * CDIM + head * CH + c]);
  float val = 0.f, v = -INFINITY;
  if (lane < CH) {
    float kn = sqrtf(nk[b * CDIM + head * CH + lane]);
    val = G[r * CH + lane] / (qn * kn) * t;
    v = val;
  }
  float m = v;
  #pragma unroll
  for (int off = 32; off; off >>= 1) m = fmaxf(m, __shfl_xor(m, off));
  float e = (lane < CH) ? expf(val - m) : 0.f;
  float s = e;
  #pragma unroll
  for (int off = 32; off; off >>= 1) s += __shfl_xor(s, off);
  if (lane < CH) attn[r * CH + lane] = e / s;
}

// ---- Mt[b][n][k] (bf16) = sum_cc attn[b,head(k)][cc][k%48] * aow[head(k)*48+cc][n] ----
__global__ __launch_bounds__(256) void attnmat_kernel(const float* __restrict__ attn,
    const float* __restrict__ aow, bf16* __restrict__ Mt)
{
  const int b  = blockIdx.x;
  const int k0 = blockIdx.y * 16;
  for (int idx = threadIdx.x; idx < 16 * 96; idx += 256) {
    int k = k0 + idx / 96, n = idx % 96;
    int h = k / CH, kk = k % CH;
    const float* ap = attn + ((b * 2 + h) * CH) * CH + kk;  // attn[bh][cc][kk], stride CH
    const float* wp = aow + (h * CH) * CDIM + n;            // aow[h*48+cc][n], stride CDIM
    float acc = 0.f;
    #pragma unroll
    for (int cc = 0; cc < CH; ++cc) acc += ap[cc * CH] * wp[cc * CDIM];
    Mt[(long)b * CDIM * CDIM + n * CDIM + k] = f2b(acc);    // transposed, k-major
  }
}

extern "C" void kernel_launch(void* const* d_in, const int* in_sizes, int n_in,
                              void* d_out, int out_size, void* d_ws, size_t ws_size,
                              hipStream_t stream)
{
  const float* x          = (const float*)d_in[0];
  const float* ln1_g      = (const float*)d_in[1];
  const float* ln1_b      = (const float*)d_in[2];
  const float* ln2_g      = (const float*)d_in[3];
  const float* ln2_b      = (const float*)d_in[4];
  const float* qkv_w      = (const float*)d_in[5];
  const float* qkv_dw     = (const float*)d_in[6];
  const float* temp       = (const float*)d_in[7];
  const float* attn_out_w = (const float*)d_in[8];
  const float* ffn_in_w   = (const float*)d_in[9];
  const float* ffn_dw     = (const float*)d_in[10];
  const float* ffn_out_w  = (const float*)d_in[11];
  float* out = (float*)d_out;

  // workspace layout (base ~177 MB; +67 MB T2M if it fits -> batch-merged FFN)
  char* ws = (char*)d_ws;
  size_t off = 0;
  auto alloc = [&](size_t bytes) { void* p = ws + off; off += (bytes + 255) & ~(size_t)255; return p; };
  bf16*  BA  = (bf16*)alloc((size_t)NPIX * C3 * 2);    // qkv planes [3][NPIX][96]; later t1
  bf16*  BB  = (bf16*)alloc((size_t)NPIX * C3 * 2);    // qkv pre-dwconv; gram partials; later gated
  bf16*  BC  = (bf16*)alloc((size_t)NPIX * CDIM * 2);  // LN2 output (from attn epilogue)
  float* NQ  = (float*)alloc(BATCH * CDIM * 4);
  float* NK  = (float*)alloc(BATCH * CDIM * 4);
  float* G   = (float*)alloc(BATCH * HEADS * CH * CH * 4);
  float* ATT = (float*)alloc(BATCH * HEADS * CH * CH * 4);
  bf16*  MT  = (bf16*)alloc((size_t)BATCH * CDIM * CDIM * 2); // fused attn matrices, k-major bf16
  bf16*  WQ  = (bf16*)alloc(288 * 96 * 2);
  bf16*  WF1 = (bf16*)alloc(256 * 96 * 2);
  bf16*  WF2 = (bf16*)alloc(256 * 96 * 2);
  bf16*  WO  = (bf16*)alloc(96 * 256 * 2);
  float* WDW = (float*)alloc(9 * 512 * 4);             // padded f32 dw table
  bf16*  T2M = (bf16*)alloc((size_t)NPIX * 256 * 2);   // both-batch t2 (merged mode only)
  const bool merged = (off <= ws_size);                // host-side capability check

  // q/k/v plane pointers within BA
  bf16* Qp = BA;
  bf16* Kp = BA + (size_t)NPIX * 96;
  bf16* Vp = BA + (size_t)2 * NPIX * 96;

  // gram partials alias the (dead at that point) BB buffer: 256*4*(2304+96) floats = 9.8 MB
  float* GP = (float*)BB;
  float* NP = GP + (size_t)256 * 4 * 2304;

  // one-shot weight transposes (k-major bf16) + padded dw table
  prep_wt<<<414, 256, 0, stream>>>(qkv_w, ffn_in_w, ffn_out_w, ffn_dw,
                                   WQ, WF1, WF2, WO, WDW);

  // ---- attention branch ----
  // qkv = dwconv(LN1(x) @ qkv_w), written as q/k/v planes
  mfma_gemm_lnA<<<NPIX / 128, 256, 0, stream>>>(x, ln1_g, ln1_b, WQ, BB);
  dwconv_plane<<<dim3(16, 64, 3), 384, 0, stream>>>(BB, qkv_dw, BA);
  gram_kernel<<<dim3(256, 4), 256, 0, stream>>>(Qp, Kp, GP, NP);
  gram_reduce<<<dim3(4, 10), 256, 0, stream>>>(GP, NP, G, NQ, NK);
  softmax_kernel<<<192, 64, 0, stream>>>(G, NQ, NK, temp, ATT);
  attnmat_kernel<<<dim3(2, 6), 256, 0, stream>>>(ATT, attn_out_w, MT);
  // out = x + v @ M_b;  BC = LN2(out)
  mfma_gemm_attn<<<NPIX / 128, 256, 0, stream>>>(
      Vp, MT, x, ln2_g, ln2_b, out, BC);

  // ---- FFN branch ----
  if (merged) {
    // both batches in single dispatches: t1 = BA (67 MB), t2 = T2M, gated = BB
    mfma_gemm_ffn<<<dim3(NPIX / 128, 1, 4), 256, 0, stream>>>(BC, WF1, WF2, BA, T2M);
    dwgate512<<<dim3(16, 64, 4), 512, 0, stream>>>(BA, T2M, WDW, BB);
  } else {
    // per-batch fallback: t1/t2 planes inside BA
    for (int b = 0; b < BATCH; ++b) {
      const bf16* bc = BC + (size_t)b * HWSZ * CDIM;
      bf16* t1    = BA;
      bf16* t2    = BA + (size_t)HWSZ * 256;
      bf16* gated = BB + (size_t)b * HWSZ * 256;
      mfma_gemm_ffn<<<dim3(HWSZ / 128, 1, 4), 256, 0, stream>>>(bc, WF1, WF2, t1, t2);
      dwgate512<<<dim3(16, 32, 4), 512, 0, stream>>>(t1, t2, WDW, gated);
    }
  }
  mfma_gemm_out<<<NPIX / 128, 256, 0, stream>>>(BB, WO, out, out);
}

// Round 20
// 422.882 us; speedup vs baseline: 1.0412x; 1.0412x over previous
//
#include <hip/hip_runtime.h>
#include <hip/hip_bf16.h>

typedef __hip_bfloat16 bf16;
typedef __attribute__((ext_vector_type(8))) short short8;
typedef __attribute__((ext_vector_type(4))) float floatx4;

#define NPIX  131072
#define BATCH 2
#define HH    256
#define WW    256
#define CDIM  96
#define C3    288
#define HEADS 2
#define CH    48
#define HIDN  255
#define HWSZ  65536
#define EPSV  1e-5f

__device__ __forceinline__ float b2f(bf16 v) { return __bfloat162float(v); }
__device__ __forceinline__ bf16  f2b(float v) { return __float2bfloat16(v); }
__device__ __forceinline__ short f2bs(float v) { bf16 h = __float2bfloat16(v); return *reinterpret_cast<short*>(&h); }
__device__ __forceinline__ float lo16(unsigned u) { return __uint_as_float(u << 16); }
__device__ __forceinline__ float hi16(unsigned u) { return __uint_as_float(u & 0xffff0000u); }
__device__ __forceinline__ unsigned packbf(float lo, float hi) {
  return ((unsigned)(unsigned short)f2bs(hi) << 16) | (unsigned)(unsigned short)f2bs(lo);
}

// exact-erf gelu via Abramowitz-Stegun 7.1.26 (|err| <= 1.5e-7)
__device__ __forceinline__ float fast_gelu(float x) {
  float ax = fabsf(x) * 0.70710678118654752440f;
  float t  = 1.f / (1.f + 0.3275911f * ax);
  float p  = ((((1.061405429f * t - 1.453152027f) * t + 1.421413741f) * t
               - 0.284496736f) * t + 0.254829592f) * t;
  float er = 1.f - p * __expf(-ax * ax);
  er = copysignf(er, x);
  return 0.5f * x * (1.f + er);
}

// ======== One-shot weight transpose to k-major bf16 (+ padded f32 dw table) ====
__global__ __launch_bounds__(256) void prep_wt(
    const float* __restrict__ qkv_w, const float* __restrict__ ffn_in_w,
    const float* __restrict__ ffn_out_w, const float* __restrict__ ffn_dw,
    bf16* __restrict__ WQ, bf16* __restrict__ WF1, bf16* __restrict__ WF2,
    bf16* __restrict__ WO, float* __restrict__ WDW)
{
  int gid = blockIdx.x * 256 + threadIdx.x;
  if (gid < 27648) {                       // 288*96
    int n = gid / 96, k = gid - n * 96;
    WQ[gid] = f2b(qkv_w[k * C3 + n]);
  } else if (gid < 27648 + 24576) {        // 256*96
    int g = gid - 27648;
    int n = g / 96, k = g - n * 96;
    WF1[g] = f2b(n < HIDN ? ffn_in_w[k * (2 * HIDN) + n] : 0.f);
  } else if (gid < 27648 + 49152) {
    int g = gid - 27648 - 24576;
    int n = g / 96, k = g - n * 96;
    WF2[g] = f2b(n < HIDN ? ffn_in_w[k * (2 * HIDN) + HIDN + n] : 0.f);
  } else if (gid < 101376) {               // 96*256
    int g = gid - 27648 - 49152;
    int n = g / 256, k = g - n * 256;
    WO[g] = f2b(k < HIDN ? ffn_out_w[k * CDIM + n] : 0.f);
  } else {                                 // WDW [9][512] f32, cols 255/511 = 0
    int idx = gid - 101376;                // 0..4607
    if (idx < 4608) {
      int c = idx & 511;
      float v = 0.f;
      if (c < 255)                 v = ffn_dw[(idx >> 9) * 510 + c];
      else if (c >= 256 && c < 511) v = ffn_dw[(idx >> 9) * 510 + (c - 1)];
      WDW[idx] = v;
    }
  }
}

// ======== FFN-out GEMM, two-phase K-split LDS panel (r16) ========
__global__ __launch_bounds__(256, 2) void mfma_gemm_out(
    const bf16* __restrict__ A, const bf16* __restrict__ Wt,  // Wt [96][256]
    const float* __restrict__ res, float* __restrict__ outp)
{
  constexpr int KP = 136;
  __shared__ __align__(16) bf16 Bs[96 * KP];      // 26.1 KB
  const int tid  = threadIdx.x;
  const long bm  = (long)blockIdx.x * 128;
  const int lane = tid & 63;
  const int wv   = tid >> 6;
  const int m15  = lane & 15;
  const int quad = lane >> 4;

  short8 areg[2][8];
  #pragma unroll
  for (int rt = 0; rt < 2; ++rt) {
    const bf16* ap = A + (bm + wv * 32 + rt * 16 + m15) * 256 + quad * 8;
    #pragma unroll
    for (int kk = 0; kk < 8; ++kk)
      areg[rt][kk] = *reinterpret_cast<const short8*>(ap + kk * 32);
  }

  floatx4 acc[2][6];
  #pragma unroll
  for (int rt = 0; rt < 2; ++rt)
    #pragma unroll
    for (int ct = 0; ct < 6; ++ct)
      acc[rt][ct] = (floatx4){0.f, 0.f, 0.f, 0.f};

  #pragma unroll 1
  for (int half = 0; half < 2; ++half) {
    if (half) __syncthreads();             // drain reads of previous half
    for (int idx = tid; idx < 96 * 16; idx += 256) {
      int n = idx >> 4, seg = idx & 15;
      *reinterpret_cast<uint4*>(&Bs[n * KP + seg * 8]) =
          *reinterpret_cast<const uint4*>(Wt + n * 256 + half * 128 + seg * 8);
    }
    __syncthreads();
    #pragma unroll
    for (int kk = 0; kk < 4; ++kk)
      #pragma unroll
      for (int ct = 0; ct < 6; ++ct) {
        short8 b = *reinterpret_cast<const short8*>(&Bs[(ct * 16 + m15) * KP + kk * 32 + quad * 8]);
        #pragma unroll
        for (int rt = 0; rt < 2; ++rt)
          acc[rt][ct] = __builtin_amdgcn_mfma_f32_16x16x32_bf16(areg[rt][half * 4 + kk], b, acc[rt][ct], 0, 0, 0);
      }
  }

  #pragma unroll
  for (int rt = 0; rt < 2; ++rt)
    #pragma unroll
    for (int ct = 0; ct < 6; ++ct) {
      int col = ct * 16 + m15;
      #pragma unroll
      for (int r = 0; r < 4; ++r) {
        long row = bm + wv * 32 + rt * 16 + quad * 4 + r;
        outp[row * CDIM + col] = acc[rt][ct][r] + res[row * CDIM + col];
      }
    }
}

// ======== FFN-in GEMM, LDS-staged weight panel (r14) ========
__global__ __launch_bounds__(256, 2) void mfma_gemm_ffn(
    const bf16* __restrict__ A,
    const bf16* __restrict__ Wt1, const bf16* __restrict__ Wt2,
    bf16* __restrict__ out1, bf16* __restrict__ out2)
{
  constexpr int KP = 104;
  __shared__ __align__(16) bf16 Bs[128 * KP];     // 26.6 KB
  const bf16* Wt  = (blockIdx.z & 2) ? Wt2 : Wt1;
  bf16* outp      = (blockIdx.z & 2) ? out2 : out1;
  const int nh    = (blockIdx.z & 1) * 128;       // column half
  const int tid  = threadIdx.x;
  const long bm  = (long)blockIdx.x * 128;
  const int lane = tid & 63;
  const int wv   = tid >> 6;
  const int m15  = lane & 15;
  const int quad = lane >> 4;

  for (int idx = tid; idx < 128 * 12; idx += 256) {
    int n = idx / 12, seg = idx - n * 12;
    *reinterpret_cast<uint4*>(&Bs[n * KP + seg * 8]) =
        *reinterpret_cast<const uint4*>(Wt + (nh + n) * 96 + seg * 8);
  }

  short8 areg[2][3];
  #pragma unroll
  for (int rt = 0; rt < 2; ++rt) {
    const bf16* ap = A + (bm + wv * 32 + rt * 16 + m15) * CDIM + quad * 8;
    #pragma unroll
    for (int kk = 0; kk < 3; ++kk)
      areg[rt][kk] = *reinterpret_cast<const short8*>(ap + kk * 32);
  }

  __syncthreads();

  floatx4 acc[2][8];
  #pragma unroll
  for (int rt = 0; rt < 2; ++rt)
    #pragma unroll
    for (int ct = 0; ct < 8; ++ct)
      acc[rt][ct] = (floatx4){0.f, 0.f, 0.f, 0.f};

  #pragma unroll
  for (int kk = 0; kk < 3; ++kk)
    #pragma unroll
    for (int ct = 0; ct < 8; ++ct) {
      short8 b = *reinterpret_cast<const short8*>(&Bs[(ct * 16 + m15) * KP + kk * 32 + quad * 8]);
      #pragma unroll
      for (int rt = 0; rt < 2; ++rt)
        acc[rt][ct] = __builtin_amdgcn_mfma_f32_16x16x32_bf16(areg[rt][kk], b, acc[rt][ct], 0, 0, 0);
    }

  #pragma unroll
  for (int rt = 0; rt < 2; ++rt)
    #pragma unroll
    for (int ct = 0; ct < 8; ++ct) {
      int col = nh + ct * 16 + m15;
      #pragma unroll
      for (int r = 0; r < 4; ++r) {
        long row = bm + wv * 32 + rt * 16 + quad * 4 + r;
        outp[row * 256 + col] = f2b(acc[rt][ct][r]);
      }
    }
}

// ======== qkv GEMM + fused LN, two-phase N-split panel (r17) ========
__global__ __launch_bounds__(256, 2) void mfma_gemm_lnA(
    const float* __restrict__ X, const float* __restrict__ gam, const float* __restrict__ bet,
    const bf16* __restrict__ Wt,   // [288][96]
    bf16* __restrict__ outp)
{
  constexpr int KP = 104;
  __shared__ __align__(16) bf16 Bs[144 * KP];     // 30.0 KB
  const int tid  = threadIdx.x;
  const long bm  = (long)blockIdx.x * 128;
  const int lane = tid & 63;
  const int wv   = tid >> 6;
  const int m15  = lane & 15;
  const int quad = lane >> 4;

  // stage phase-0 panel (rows 0..143); overlaps with LN math below
  for (int idx = tid; idx < 144 * 12; idx += 256) {
    int n = idx / 12, seg = idx - n * 12;
    *reinterpret_cast<uint4*>(&Bs[n * KP + seg * 8]) =
        *reinterpret_cast<const uint4*>(Wt + n * 96 + seg * 8);
  }

  float xv[2][24];
  #pragma unroll
  for (int rt = 0; rt < 2; ++rt) {
    const float* xp = X + (bm + wv * 32 + rt * 16 + m15) * CDIM + quad * 8;
    #pragma unroll
    for (int kk = 0; kk < 3; ++kk) {
      float4 t0 = *reinterpret_cast<const float4*>(xp + kk * 32);
      float4 t1 = *reinterpret_cast<const float4*>(xp + kk * 32 + 4);
      xv[rt][kk * 8 + 0] = t0.x; xv[rt][kk * 8 + 1] = t0.y; xv[rt][kk * 8 + 2] = t0.z; xv[rt][kk * 8 + 3] = t0.w;
      xv[rt][kk * 8 + 4] = t1.x; xv[rt][kk * 8 + 5] = t1.y; xv[rt][kk * 8 + 6] = t1.z; xv[rt][kk * 8 + 7] = t1.w;
    }
  }
  float gv[24], bv[24];
  #pragma unroll
  for (int kk = 0; kk < 3; ++kk) {
    float4 g0 = *reinterpret_cast<const float4*>(gam + kk * 32 + quad * 8);
    float4 g1 = *reinterpret_cast<const float4*>(gam + kk * 32 + quad * 8 + 4);
    float4 b0 = *reinterpret_cast<const float4*>(bet + kk * 32 + quad * 8);
    float4 b1 = *reinterpret_cast<const float4*>(bet + kk * 32 + quad * 8 + 4);
    gv[kk * 8 + 0] = g0.x; gv[kk * 8 + 1] = g0.y; gv[kk * 8 + 2] = g0.z; gv[kk * 8 + 3] = g0.w;
    gv[kk * 8 + 4] = g1.x; gv[kk * 8 + 5] = g1.y; gv[kk * 8 + 6] = g1.z; gv[kk * 8 + 7] = g1.w;
    bv[kk * 8 + 0] = b0.x; bv[kk * 8 + 1] = b0.y; bv[kk * 8 + 2] = b0.z; bv[kk * 8 + 3] = b0.w;
    bv[kk * 8 + 4] = b1.x; bv[kk * 8 + 5] = b1.y; bv[kk * 8 + 6] = b1.z; bv[kk * 8 + 7] = b1.w;
  }

  short8 areg[2][3];
  #pragma unroll
  for (int rt = 0; rt < 2; ++rt) {
    float s = 0.f, sq = 0.f;
    #pragma unroll
    for (int e = 0; e < 24; ++e) { s += xv[rt][e]; sq += xv[rt][e] * xv[rt][e]; }
    s  += __shfl_xor(s, 16);  s  += __shfl_xor(s, 32);
    sq += __shfl_xor(sq, 16); sq += __shfl_xor(sq, 32);
    float mean = s * (1.f / 96.f);
    float var  = sq * (1.f / 96.f) - mean * mean;
    float rstd = rsqrtf(var + EPSV);
    #pragma unroll
    for (int kk = 0; kk < 3; ++kk)
      #pragma unroll
      for (int j = 0; j < 8; ++j)
        areg[rt][kk][j] = f2bs((xv[rt][kk * 8 + j] - mean) * rstd * gv[kk * 8 + j] + bv[kk * 8 + j]);
  }

  #pragma unroll 1
  for (int ph = 0; ph < 2; ++ph) {
    if (ph) {
      __syncthreads();                     // drain phase-0 panel reads
      for (int idx = tid; idx < 144 * 12; idx += 256) {
        int n = idx / 12, seg = idx - n * 12;
        *reinterpret_cast<uint4*>(&Bs[n * KP + seg * 8]) =
            *reinterpret_cast<const uint4*>(Wt + (144 + n) * 96 + seg * 8);
      }
    }
    __syncthreads();

    floatx4 acc[2][9];
    #pragma unroll
    for (int rt = 0; rt < 2; ++rt)
      #pragma unroll
      for (int ct = 0; ct < 9; ++ct)
        acc[rt][ct] = (floatx4){0.f, 0.f, 0.f, 0.f};

    #pragma unroll
    for (int kk = 0; kk < 3; ++kk)
      #pragma unroll
      for (int ct = 0; ct < 9; ++ct) {
        short8 b = *reinterpret_cast<const short8*>(&Bs[(ct * 16 + m15) * KP + kk * 32 + quad * 8]);
        #pragma unroll
        for (int rt = 0; rt < 2; ++rt)
          acc[rt][ct] = __builtin_amdgcn_mfma_f32_16x16x32_bf16(areg[rt][kk], b, acc[rt][ct], 0, 0, 0);
      }

    #pragma unroll
    for (int rt = 0; rt < 2; ++rt)
      #pragma unroll
      for (int ct = 0; ct < 9; ++ct) {
        int col = ph * 144 + ct * 16 + m15;
        #pragma unroll
        for (int r = 0; r < 4; ++r) {
          long row = bm + wv * 32 + rt * 16 + quad * 4 + r;
          outp[row * C3 + col] = f2b(acc[rt][ct][r]);
        }
      }
  }
}

// ======== attn-out GEMM (v-plane @ M_b^T) + residual + fused LN2, staged Mt ====
__global__ __launch_bounds__(256, 2) void mfma_gemm_attn(
    const bf16* __restrict__ A, const bf16* __restrict__ Mt,
    const float* __restrict__ res, const float* __restrict__ gam, const float* __restrict__ bet,
    float* __restrict__ outp, bf16* __restrict__ y2)
{
  constexpr int KP = 104;
  __shared__ __align__(16) bf16 Bs[96 * KP];      // 20 KB
  const int tid  = threadIdx.x;
  const long bm  = (long)blockIdx.x * 128;
  const int lane = tid & 63;
  const int wv   = tid >> 6;
  const int m15  = lane & 15;
  const int quad = lane >> 4;

  const bf16* mp = Mt + (bm >> 16) * (CDIM * CDIM);
  for (int idx = tid; idx < 96 * 12; idx += 256) {
    int n = idx / 12, seg = idx - n * 12;
    *reinterpret_cast<uint4*>(&Bs[n * KP + seg * 8]) =
        *reinterpret_cast<const uint4*>(mp + n * 96 + seg * 8);
  }

  short8 areg[2][3];
  #pragma unroll
  for (int rt = 0; rt < 2; ++rt) {
    const bf16* ap = A + (bm + wv * 32 + rt * 16 + m15) * 96 + quad * 8;
    #pragma unroll
    for (int kk = 0; kk < 3; ++kk)
      areg[rt][kk] = *reinterpret_cast<const short8*>(ap + kk * 32);
  }

  __syncthreads();

  floatx4 acc[2][6];
  #pragma unroll
  for (int rt = 0; rt < 2; ++rt)
    #pragma unroll
    for (int ct = 0; ct < 6; ++ct)
      acc[rt][ct] = (floatx4){0.f, 0.f, 0.f, 0.f};

  #pragma unroll
  for (int kk = 0; kk < 3; ++kk)
    #pragma unroll
    for (int ct = 0; ct < 6; ++ct) {
      short8 b = *reinterpret_cast<const short8*>(&Bs[(ct * 16 + m15) * KP + kk * 32 + quad * 8]);
      #pragma unroll
      for (int rt = 0; rt < 2; ++rt)
        acc[rt][ct] = __builtin_amdgcn_mfma_f32_16x16x32_bf16(areg[rt][kk], b, acc[rt][ct], 0, 0, 0);
    }

  float gv[6], bv[6];
  #pragma unroll
  for (int ct = 0; ct < 6; ++ct) { gv[ct] = gam[ct * 16 + m15]; bv[ct] = bet[ct * 16 + m15]; }

  #pragma unroll
  for (int rt = 0; rt < 2; ++rt)
    #pragma unroll
    for (int r = 0; r < 4; ++r) {
      long row = bm + wv * 32 + rt * 16 + quad * 4 + r;
      float v[6];
      float s = 0.f, sq = 0.f;
      #pragma unroll
      for (int ct = 0; ct < 6; ++ct) {
        v[ct] = acc[rt][ct][r] + res[row * CDIM + ct * 16 + m15];
        s += v[ct]; sq += v[ct] * v[ct];
      }
      #pragma unroll
      for (int off = 8; off; off >>= 1) { s += __shfl_xor(s, off); sq += __shfl_xor(sq, off); }
      float mean = s * (1.f / 96.f);
      float var  = sq * (1.f / 96.f) - mean * mean;
      float rstd = rsqrtf(var + EPSV);
      #pragma unroll
      for (int ct = 0; ct < 6; ++ct) {
        int col = ct * 16 + m15;
        outp[row * CDIM + col] = v[ct];
        y2[row * CDIM + col] = f2b((v[ct] - mean) * rstd * gv[ct] + bv[ct]);
      }
    }
}

// ======== qkv depthwise 3x3 conv -> plane-major output [3][NPIX][96] ========
// Barrier-free per-wave slices; weights via wave-uniform s_load (SGPRs).
__global__ __launch_bounds__(384, 2) void dwconv_plane(
    const bf16* __restrict__ in,      // [NPIX][288] pre-dwconv qkv
    const float* __restrict__ kw,     // qkv_dw [9][288] f32
    bf16* __restrict__ outbase)       // [3][NPIX][96]
{
  __shared__ uint4 sm[12][19 * 10];
  const int tid = threadIdx.x;
  const int tx0 = blockIdx.x * 16;
  const int ty0 = (blockIdx.y & 31) * 8;
  const int b   = blockIdx.y >> 5;
  const int pl  = blockIdx.z;        // 0=q 1=k 2=v
  const int c0  = pl * 96;
  const long bbase = (long)b * HWSZ;
  bf16* out = outbase + (size_t)pl * NPIX * 96;

  const int lane = tid & 63;
  const int wv   = tid >> 6;         // 0..5

  // per-wave staging: wave wv owns slices wv and wv+6
  for (int f = lane; f < 180; f += 64) {
    int row = f / 18, px = f - row * 18;
    int y = ty0 + row - 1, xx = tx0 + px - 1;
    uint4 ua = make_uint4(0u, 0u, 0u, 0u), ub = ua;
    if ((unsigned)y < (unsigned)HH && (unsigned)xx < (unsigned)WW) {
      const bf16* p = in + (bbase + (long)y * WW + xx) * C3 + c0;
      ua = *reinterpret_cast<const uint4*>(p + wv * 8);
      ub = *reinterpret_cast<const uint4*>(p + (wv + 6) * 8);
    }
    sm[wv][row * 19 + px]     = ua;
    sm[wv + 6][row * 19 + px] = ub;
  }
  asm volatile("s_waitcnt lgkmcnt(0)" ::: "memory");
  __builtin_amdgcn_sched_barrier(0);

  const int x  = lane & 15;
  const int yg = lane >> 4;          // 0..3, 2 output rows per thread

  #pragma unroll 1
  for (int cgi = 0; cgi < 2; ++cgi) {
    const int cg = wv + cgi * 6;     // 0..11
    // wave-uniform channel base -> scalar (s_load) weight fetch
    const int cbu = __builtin_amdgcn_readfirstlane(c0 + cg * 8);
    float wgt[9][8];
    #pragma unroll
    for (int t = 0; t < 9; ++t) {
      float4 w0 = *reinterpret_cast<const float4*>(kw + t * C3 + cbu);
      float4 w1 = *reinterpret_cast<const float4*>(kw + t * C3 + cbu + 4);
      wgt[t][0] = w0.x; wgt[t][1] = w0.y; wgt[t][2] = w0.z; wgt[t][3] = w0.w;
      wgt[t][4] = w1.x; wgt[t][5] = w1.y; wgt[t][6] = w1.z; wgt[t][7] = w1.w;
    }
    #pragma unroll
    for (int yy = 0; yy < 2; ++yy) {
      const int ry = yg * 2 + yy;
      float acc[8] = {0.f, 0.f, 0.f, 0.f, 0.f, 0.f, 0.f, 0.f};
      #pragma unroll
      for (int dy = 0; dy < 3; ++dy)
        #pragma unroll
        for (int dx = 0; dx < 3; ++dx) {
          uint4 u = sm[cg][(ry + dy) * 19 + x + dx];
          const float* wt = wgt[dy * 3 + dx];
          acc[0] += lo16(u.x) * wt[0]; acc[1] += hi16(u.x) * wt[1];
          acc[2] += lo16(u.y) * wt[2]; acc[3] += hi16(u.y) * wt[3];
          acc[4] += lo16(u.z) * wt[4]; acc[5] += hi16(u.z) * wt[5];
          acc[6] += lo16(u.w) * wt[6]; acc[7] += hi16(u.w) * wt[7];
        }
      bf16* op = out + (bbase + (long)(ty0 + ry) * WW + tx0 + x) * 96 + cg * 8;
      __align__(16) bf16 ov[8];
      #pragma unroll
      for (int j = 0; j < 8; ++j) ov[j] = f2b(acc[j]);
      *reinterpret_cast<uint4*>(op) = *reinterpret_cast<const uint4*>(ov);
    }
    __builtin_amdgcn_sched_barrier(0);   // one wgt set live at a time
  }
}

// ======== Fused FFN gate v5: 512 thr, 64 ch/block, two-phase restage ========
__global__ __launch_bounds__(512, 2) void dwgate512(
    const bf16* __restrict__ t1, const bf16* __restrict__ t2,
    const float* __restrict__ wdw, bf16* __restrict__ out)
{
  __shared__ uint4 sm[8][19 * 10];
  const int tid = threadIdx.x;
  const int tx0 = blockIdx.x * 16;
  const int ty0 = (blockIdx.y & 31) * 8;
  const long bbase = (long)(blockIdx.y >> 5) * HWSZ;
  const int c0  = blockIdx.z * 64;

  const int lane = tid & 63;
  const int wv   = tid >> 6;         // 0..7 = this wave's ch-group
  const int cb   = c0 + wv * 8;
  const int cbu  = __builtin_amdgcn_readfirstlane(cb);

  // ---- stage t1 into this wave's slice; preload t2 into regs (async split) ----
  uint4 t2r[3];
  #pragma unroll
  for (int i = 0; i < 3; ++i) {
    int f = lane + i * 64;
    int row = f / 18, px = f - row * 18;
    int y = ty0 + row - 1, xx = tx0 + px - 1;
    bool ok = (f < 180) && ((unsigned)y < (unsigned)HH) && ((unsigned)xx < (unsigned)WW);
    long base = (bbase + (long)y * WW + xx) * 256 + cb;
    uint4 u1 = make_uint4(0u, 0u, 0u, 0u);
    t2r[i]   = make_uint4(0u, 0u, 0u, 0u);
    if (ok) {
      u1     = *reinterpret_cast<const uint4*>(t1 + base);
      t2r[i] = *reinterpret_cast<const uint4*>(t2 + base);
    }
    if (f < 180) sm[wv][row * 19 + px] = u1;
  }
  asm volatile("s_waitcnt lgkmcnt(0)" ::: "memory");
  __builtin_amdgcn_sched_barrier(0);

  const int x  = lane & 15;
  const int yg = lane >> 4;          // 0..3, 2 output rows per thread

  unsigned gp[8];                    // gelu(conv1) packed 2xbf16 [yy*4+pair]
  float wgt[9][8];

  // ---- pass 1: conv t1 (sm[wv]) -> gelu, packed regs ----
  #pragma unroll
  for (int t = 0; t < 9; ++t) {
    float4 w0 = *reinterpret_cast<const float4*>(wdw + t * 512 + cbu);
    float4 w1 = *reinterpret_cast<const float4*>(wdw + t * 512 + cbu + 4);
    wgt[t][0] = w0.x; wgt[t][1] = w0.y; wgt[t][2] = w0.z; wgt[t][3] = w0.w;
    wgt[t][4] = w1.x; wgt[t][5] = w1.y; wgt[t][6] = w1.z; wgt[t][7] = w1.w;
  }
  #pragma unroll
  for (int yy = 0; yy < 2; ++yy) {
    const int ry = yg * 2 + yy;
    float acc[8] = {0.f, 0.f, 0.f, 0.f, 0.f, 0.f, 0.f, 0.f};
    #pragma unroll
    for (int dy = 0; dy < 3; ++dy)
      #pragma unroll
      for (int dx = 0; dx < 3; ++dx) {
        uint4 u = sm[wv][(ry + dy) * 19 + x + dx];
        const float* wt = wgt[dy * 3 + dx];
        acc[0] += lo16(u.x) * wt[0]; acc[1] += hi16(u.x) * wt[1];
        acc[2] += lo16(u.y) * wt[2]; acc[3] += hi16(u.y) * wt[3];
        acc[4] += lo16(u.z) * wt[4]; acc[5] += hi16(u.z) * wt[5];
        acc[6] += lo16(u.w) * wt[6]; acc[7] += hi16(u.w) * wt[7];
      }
    #pragma unroll
    for (int p = 0; p < 4; ++p)
      gp[yy * 4 + p] = packbf(fast_gelu(acc[2 * p]), fast_gelu(acc[2 * p + 1]));
  }

  // ---- restage t2 into the same slice (pass-1 reads consumed; DS in-order) ----
  asm volatile("s_waitcnt lgkmcnt(0)" ::: "memory");
  __builtin_amdgcn_sched_barrier(0);
  #pragma unroll
  for (int i = 0; i < 3; ++i) {
    int f = lane + i * 64;
    int row = f / 18, px = f - row * 18;
    if (f < 180) sm[wv][row * 19 + px] = t2r[i];
  }
  asm volatile("s_waitcnt lgkmcnt(0)" ::: "memory");
  __builtin_amdgcn_sched_barrier(0);

  // ---- pass 2: conv t2 (sm[wv]), multiply, store ----
  #pragma unroll
  for (int t = 0; t < 9; ++t) {
    float4 w0 = *reinterpret_cast<const float4*>(wdw + t * 512 + 256 + cbu);
    float4 w1 = *reinterpret_cast<const float4*>(wdw + t * 512 + 256 + cbu + 4);
    wgt[t][0] = w0.x; wgt[t][1] = w0.y; wgt[t][2] = w0.z; wgt[t][3] = w0.w;
    wgt[t][4] = w1.x; wgt[t][5] = w1.y; wgt[t][6] = w1.z; wgt[t][7] = w1.w;
  }
  #pragma unroll
  for (int yy = 0; yy < 2; ++yy) {
    const int ry = yg * 2 + yy;
    float acc[8] = {0.f, 0.f, 0.f, 0.f, 0.f, 0.f, 0.f, 0.f};
    #pragma unroll
    for (int dy = 0; dy < 3; ++dy)
      #pragma unroll
      for (int dx = 0; dx < 3; ++dx) {
        uint4 u = sm[wv][(ry + dy) * 19 + x + dx];
        const float* wt = wgt[dy * 3 + dx];
        acc[0] += lo16(u.x) * wt[0]; acc[1] += hi16(u.x) * wt[1];
        acc[2] += lo16(u.y) * wt[2]; acc[3] += hi16(u.y) * wt[3];
        acc[4] += lo16(u.z) * wt[4]; acc[5] += hi16(u.z) * wt[5];
        acc[6] += lo16(u.w) * wt[6]; acc[7] += hi16(u.w) * wt[7];
      }
    bf16* op = out + (bbase + (long)(ty0 + ry) * WW + tx0 + x) * 256 + cb;
    __align__(16) bf16 ov[8];
    #pragma unroll
    for (int p = 0; p < 4; ++p) {
      ov[2 * p]     = f2b(lo16(gp[yy * 4 + p]) * acc[2 * p]);
      ov[2 * p + 1] = f2b(hi16(gp[yy * 4 + p]) * acc[2 * p + 1]);
    }
    *reinterpret_cast<uint4*>(op) = *reinterpret_cast<const uint4*>(ov);
  }
}

// ======== MFMA Gram + fused q/k L2 norms — q/k planes [NPIX][96] ========
__global__ __launch_bounds__(256) void gram_kernel(
    const bf16* __restrict__ Qp, const bf16* __restrict__ Kp,
    float* __restrict__ Gpart, float* __restrict__ Npart)
{
  constexpr int SP = 264;
  __shared__ __align__(16) char raw[2 * CH * SP * 2];   // 50688 B
  short* qs = (short*)raw;              // [48][SP]
  short* ks = qs + CH * SP;
  const int tid  = threadIdx.x;
  const int bh   = blockIdx.y;
  const long row0 = (long)(bh >> 1) * HWSZ + (long)blockIdx.x * 256;
  const int head = bh & 1;
  const int lane = tid & 63;
  const int wv   = tid >> 6;
  const int m15  = lane & 15;
  const int quad = lane >> 4;

  {
    const short* qsrc = (const short*)(Qp + (row0 + tid) * 96 + head * CH);
    const short* ksrc = (const short*)(Kp + (row0 + tid) * 96 + head * CH);
    #pragma unroll
    for (int v = 0; v < 6; ++v) {
      short8 q8 = *reinterpret_cast<const short8*>(qsrc + v * 8);
      short8 k8 = *reinterpret_cast<const short8*>(ksrc + v * 8);
      #pragma unroll
      for (int j = 0; j < 8; ++j) {
        qs[(v * 8 + j) * SP + tid] = q8[j];
        ks[(v * 8 + j) * SP + tid] = k8[j];
      }
    }
  }
  __syncthreads();

  floatx4 acc[3][3], accq[3], acck[3];
  #pragma unroll
  for (int i = 0; i < 3; ++i) {
    accq[i] = (floatx4){0.f, 0.f, 0.f, 0.f};
    acck[i] = (floatx4){0.f, 0.f, 0.f, 0.f};
    #pragma unroll
    for (int j = 0; j < 3; ++j) acc[i][j] = (floatx4){0.f, 0.f, 0.f, 0.f};
  }

  #pragma unroll
  for (int kk = 0; kk < 2; ++kk) {
    const int s_off = wv * 64 + kk * 32 + quad * 8;
    short8 aq[3], bk[3];
    #pragma unroll
    for (int i = 0; i < 3; ++i) {
      aq[i] = *reinterpret_cast<const short8*>(&qs[(i * 16 + m15) * SP + s_off]);
      bk[i] = *reinterpret_cast<const short8*>(&ks[(i * 16 + m15) * SP + s_off]);
    }
    #pragma unroll
    for (int i = 0; i < 3; ++i) {
      accq[i] = __builtin_amdgcn_mfma_f32_16x16x32_bf16(aq[i], aq[i], accq[i], 0, 0, 0);
      acck[i] = __builtin_amdgcn_mfma_f32_16x16x32_bf16(bk[i], bk[i], acck[i], 0, 0, 0);
      #pragma unroll
      for (int j = 0; j < 3; ++j)
        acc[i][j] = __builtin_amdgcn_mfma_f32_16x16x32_bf16(aq[i], bk[j], acc[i][j], 0, 0, 0);
    }
  }

  __syncthreads();
  float* part  = (float*)raw;            // [4][48*49] = 9408 floats
  float* npart = part + 4 * 48 * 49;     // [4][96]
  const int c_lo = quad * 4;
  #pragma unroll
  for (int i = 0; i < 3; ++i)
    #pragma unroll
    for (int j = 0; j < 3; ++j)
      #pragma unroll
      for (int r = 0; r < 4; ++r)
        part[wv * 2352 + (i * 16 + c_lo + r) * 49 + j * 16 + m15] = acc[i][j][r];
  if (m15 >= c_lo && m15 < c_lo + 4) {
    const int r = m15 - c_lo;
    #pragma unroll
    for (int i = 0; i < 3; ++i) {
      npart[wv * 96 + i * 16 + m15]      = accq[i][r];
      npart[wv * 96 + 48 + i * 16 + m15] = acck[i][r];
    }
  }
  __syncthreads();
  float* Gp = Gpart + ((long)blockIdx.x * 4 + bh) * 2304;
  for (int f = tid; f < 2304; f += 256) {
    int row = f / 48, col = f - row * 48;
    int o = row * 49 + col;
    Gp[f] = part[o] + part[2352 + o] + part[4704 + o] + part[7056 + o];
  }
  if (tid < 96)
    Npart[((long)blockIdx.x * 4 + bh) * 96 + tid] =
        npart[tid] + npart[96 + tid] + npart[192 + tid] + npart[288 + tid];
}

// ---- sum the 256 chunk partials per bh into G / nq / nk ----
__global__ __launch_bounds__(256) void gram_reduce(const float* __restrict__ Gpart,
    const float* __restrict__ Npart, float* __restrict__ G,
    float* __restrict__ nq, float* __restrict__ nk)
{
  const int bh = blockIdx.x;
  const int b = bh >> 1, head = bh & 1;
  if (blockIdx.y < 9) {
    const int f = blockIdx.y * 256 + threadIdx.x;
    float s = 0.f;
    #pragma unroll 8
    for (int c = 0; c < 256; ++c) s += Gpart[((long)c * 4 + bh) * 2304 + f];
    G[(long)bh * 2304 + f] = s;
  } else {
    const int t = threadIdx.x;
    if (t < 96) {
      float s = 0.f;
      #pragma unroll 8
      for (int c = 0; c < 256; ++c) s += Npart[((long)c * 4 + bh) * 96 + t];
      if (t < 48) nq[b * CDIM + head * CH + t] = s;
      else        nk[b * CDIM + head * CH + t - 48] = s;
    }
  }
}

// ---------------- softmax over d of G/(|q||k|)*temp ----------------
__global__ __launch_bounds__(64) void softmax_kernel(const float* __restrict__ G,
    const float* __restrict__ nq, const float* __restrict__ nk,
    const float* __restrict__ temp, float* __restrict__ attn)
{
  int r = blockIdx.x;               // 0..191 = (b*2+head)*48 + c
  int lane = threadIdx.x;
  int bh = r / CH, c = r % CH;
  int b = bh >> 1, head = bh & 1;
  float t  = temp[head];
  float qn = sqrtf(nq[b * CDIM + head * CH + c]);
  float val = 0.f, v = -INFINITY;
  if (lane < CH) {
    float kn = sqrtf(nk[b * CDIM + head * CH + lane]);
    val = G[r * CH + lane] / (qn * kn) * t;
    v = val;
  }
  float m = v;
  #pragma unroll
  for (int off = 32; off; off >>= 1) m = fmaxf(m, __shfl_xor(m, off));
  float e = (lane < CH) ? expf(val - m) : 0.f;
  float s = e;
  #pragma unroll
  for (int off = 32; off; off >>= 1) s += __shfl_xor(s, off);
  if (lane < CH) attn[r * CH + lane] = e / s;
}

// ---- Mt[b][n][k] (bf16) = sum_cc attn[b,head(k)][cc][k%48] * aow[head(k)*48+cc][n] ----
__global__ __launch_bounds__(256) void attnmat_kernel(const float* __restrict__ attn,
    const float* __restrict__ aow, bf16* __restrict__ Mt)
{
  const int b  = blockIdx.x;
  const int k0 = blockIdx.y * 16;
  for (int idx = threadIdx.x; idx < 16 * 96; idx += 256) {
    int k = k0 + idx / 96, n = idx % 96;
    int h = k / CH, kk = k % CH;
    const float* ap = attn + ((b * 2 + h) * CH) * CH + kk;  // attn[bh][cc][kk], stride CH
    const float* wp = aow + (h * CH) * CDIM + n;            // aow[h*48+cc][n], stride CDIM
    float acc = 0.f;
    #pragma unroll
    for (int cc = 0; cc < CH; ++cc) acc += ap[cc * CH] * wp[cc * CDIM];
    Mt[(long)b * CDIM * CDIM + n * CDIM + k] = f2b(acc);    // transposed, k-major
  }
}

extern "C" void kernel_launch(void* const* d_in, const int* in_sizes, int n_in,
                              void* d_out, int out_size, void* d_ws, size_t ws_size,
                              hipStream_t stream)
{
  const float* x          = (const float*)d_in[0];
  const float* ln1_g      = (const float*)d_in[1];
  const float* ln1_b      = (const float*)d_in[2];
  const float* ln2_g      = (const float*)d_in[3];
  const float* ln2_b      = (const float*)d_in[4];
  const float* qkv_w      = (const float*)d_in[5];
  const float* qkv_dw     = (const float*)d_in[6];
  const float* temp       = (const float*)d_in[7];
  const float* attn_out_w = (const float*)d_in[8];
  const float* ffn_in_w   = (const float*)d_in[9];
  const float* ffn_dw     = (const float*)d_in[10];
  const float* ffn_out_w  = (const float*)d_in[11];
  float* out = (float*)d_out;

  // workspace layout (base ~177 MB; +67 MB T2M if it fits -> batch-merged FFN)
  char* ws = (char*)d_ws;
  size_t off = 0;
  auto alloc = [&](size_t bytes) { void* p = ws + off; off += (bytes + 255) & ~(size_t)255; return p; };
  bf16*  BA  = (bf16*)alloc((size_t)NPIX * C3 * 2);    // qkv planes [3][NPIX][96]; later t1
  bf16*  BB  = (bf16*)alloc((size_t)NPIX * C3 * 2);    // qkv pre-dwconv; gram partials; later gated
  bf16*  BC  = (bf16*)alloc((size_t)NPIX * CDIM * 2);  // LN2 output (from attn epilogue)
  float* NQ  = (float*)alloc(BATCH * CDIM * 4);
  float* NK  = (float*)alloc(BATCH * CDIM * 4);
  float* G   = (float*)alloc(BATCH * HEADS * CH * CH * 4);
  float* ATT = (float*)alloc(BATCH * HEADS * CH * CH * 4);
  bf16*  MT  = (bf16*)alloc((size_t)BATCH * CDIM * CDIM * 2); // fused attn matrices, k-major bf16
  bf16*  WQ  = (bf16*)alloc(288 * 96 * 2);
  bf16*  WF1 = (bf16*)alloc(256 * 96 * 2);
  bf16*  WF2 = (bf16*)alloc(256 * 96 * 2);
  bf16*  WO  = (bf16*)alloc(96 * 256 * 2);
  float* WDW = (float*)alloc(9 * 512 * 4);             // padded f32 dw table
  bf16*  T2M = (bf16*)alloc((size_t)NPIX * 256 * 2);   // both-batch t2 (merged mode only)
  const bool merged = (off <= ws_size);                // host-side capability check

  // q/k/v plane pointers within BA
  bf16* Qp = BA;
  bf16* Kp = BA + (size_t)NPIX * 96;
  bf16* Vp = BA + (size_t)2 * NPIX * 96;

  // gram partials alias the (dead at that point) BB buffer: 256*4*(2304+96) floats = 9.8 MB
  float* GP = (float*)BB;
  float* NP = GP + (size_t)256 * 4 * 2304;

  // one-shot weight transposes (k-major bf16) + padded dw table
  prep_wt<<<414, 256, 0, stream>>>(qkv_w, ffn_in_w, ffn_out_w, ffn_dw,
                                   WQ, WF1, WF2, WO, WDW);

  // ---- attention branch ----
  // qkv = dwconv(LN1(x) @ qkv_w), written as q/k/v planes
  mfma_gemm_lnA<<<NPIX / 128, 256, 0, stream>>>(x, ln1_g, ln1_b, WQ, BB);
  dwconv_plane<<<dim3(16, 64, 3), 384, 0, stream>>>(BB, qkv_dw, BA);
  gram_kernel<<<dim3(256, 4), 256, 0, stream>>>(Qp, Kp, GP, NP);
  gram_reduce<<<dim3(4, 10), 256, 0, stream>>>(GP, NP, G, NQ, NK);
  softmax_kernel<<<192, 64, 0, stream>>>(G, NQ, NK, temp, ATT);
  attnmat_kernel<<<dim3(2, 6), 256, 0, stream>>>(ATT, attn_out_w, MT);
  // out = x + v @ M_b;  BC = LN2(out)
  mfma_gemm_attn<<<NPIX / 128, 256, 0, stream>>>(
      Vp, MT, x, ln2_g, ln2_b, out, BC);

  // ---- FFN branch ----
  if (merged) {
    // both batches in single dispatches: t1 = BA (67 MB), t2 = T2M, gated = BB
    mfma_gemm_ffn<<<dim3(NPIX / 128, 1, 4), 256, 0, stream>>>(BC, WF1, WF2, BA, T2M);
    dwgate512<<<dim3(16, 64, 4), 512, 0, stream>>>(BA, T2M, WDW, BB);
  } else {
    // per-batch fallback: t1/t2 planes inside BA
    for (int b = 0; b < BATCH; ++b) {
      const bf16* bc = BC + (size_t)b * HWSZ * CDIM;
      bf16* t1    = BA;
      bf16* t2    = BA + (size_t)HWSZ * 256;
      bf16* gated = BB + (size_t)b * HWSZ * 256;
      mfma_gemm_ffn<<<dim3(HWSZ / 128, 1, 4), 256, 0, stream>>>(bc, WF1, WF2, t1, t2);
      dwgate512<<<dim3(16, 32, 4), 512, 0, stream>>>(t1, t2, WDW, gated);
    }
  }
  mfma_gemm_out<<<NPIX / 128, 256, 0, stream>>>(BB, WO, out, out);
}